// Round 2
// baseline (984.446 us; speedup 1.0000x reference)
//
#include <hip/hip_runtime.h>
#include <hip/hip_bf16.h>

typedef int int4v __attribute__((ext_vector_type(4)));

#define DEV __device__ __forceinline__

DEV signed char quant8(float v) {
    int q = (int)rintf(v);
    q = q < -128 ? -128 : (q > 127 ? 127 : q);
    return (signed char)q;
}

DEV int tern1(float v) {
    int q = (int)rintf(v);
    q = q < -1 ? -1 : (q > 1 ? 1 : q);
    return q;
}

DEV float blk_sum(float v, float* red) {
    int t = threadIdx.x;
    red[t] = v; __syncthreads();
    #pragma unroll
    for (int o = 128; o > 0; o >>= 1) {
        if (t < o) red[t] += red[t + o];
        __syncthreads();
    }
    float r = red[0]; __syncthreads();
    return r;
}

DEV float blk_max(float v, float* red) {
    int t = threadIdx.x;
    red[t] = v; __syncthreads();
    #pragma unroll
    for (int o = 128; o > 0; o >>= 1) {
        if (t < o) red[t] = fmaxf(red[t], red[t + o]);
        __syncthreads();
    }
    float r = red[0]; __syncthreads();
    return r;
}

// ---------------------------------------------------------------- weights ---
// Stage 1: per-block partial sum of |w| (double, deterministic tree)
__global__ __launch_bounds__(256) void absmean_partial(
    const float* __restrict__ W, double* __restrict__ part, int nper)
{
    __shared__ double red[256];
    int t = threadIdx.x;
    size_t base = (size_t)blockIdx.x * nper;
    double acc = 0.0;
    for (int i = t; i < nper; i += 256) acc += (double)fabsf(W[base + i]);
    red[t] = acc; __syncthreads();
    #pragma unroll
    for (int o = 128; o > 0; o >>= 1) {
        if (t < o) red[t] += red[t + o];
        __syncthreads();
    }
    if (t == 0) part[blockIdx.x] = red[0];
}

// Stage 2: one wave per matrix reduces 64 partials -> beta = max(mean,1e-5)
__global__ __launch_bounds__(256) void betas_kernel(
    const double* __restrict__ part, float* __restrict__ betas)
{
    int t = threadIdx.x, w = t >> 6, lane = t & 63;
    const int counts[4] = {1048576, 524288, 524288, 1048576};
    double v = part[w * 64 + lane];
    #pragma unroll
    for (int o = 32; o > 0; o >>= 1) v += __shfl_down(v, o);
    if (lane == 0) betas[w] = fmaxf((float)(v / (double)counts[w]), 1e-5f);
}

// Ternary quantize weights: t = clip(rint(w/beta), -1, 1), stored int8
__global__ __launch_bounds__(256) void wquant(
    const float* __restrict__ W, signed char* __restrict__ O,
    const float* __restrict__ betas, int mi)
{
    int i = blockIdx.x * 256 + threadIdx.x;   // one float4 per thread
    float inv = 1.f / betas[mi];
    float4 u = ((const float4*)W)[i];
    int q0 = tern1(u.x * inv);
    int q1 = tern1(u.y * inv);
    int q2 = tern1(u.z * inv);
    int q3 = tern1(u.w * inv);
    int packed = (q0 & 0xff) | ((q1 & 0xff) << 8) | ((q2 & 0xff) << 16) | ((q3 & 0xff) << 24);
    ((int*)O)[i] = packed;
}

// ------------------------------------------------------------ activations ---
// Per-token (row of 1024): rms_norm then absmax int8 quant. One block/row.
__global__ __launch_bounds__(256) void act_quant(
    const float* __restrict__ X, signed char* __restrict__ X8,
    float* __restrict__ RS)
{
    __shared__ float red[256];
    int row = blockIdx.x, t = threadIdx.x;
    const float* xr = X + (size_t)row * 1024;
    float4 u = ((const float4*)xr)[t];
    float v0 = u.x, v1 = u.y, v2 = u.z, v3 = u.w;
    float ss = v0 * v0 + v1 * v1 + v2 * v2 + v3 * v3;
    float am = fmaxf(fmaxf(fabsf(v0), fabsf(v1)), fmaxf(fabsf(v2), fabsf(v3)));
    float tot = blk_sum(ss, red);
    float amax = blk_max(am, red);
    float r = 1.f / sqrtf(tot * (1.f / 1024.f) + 1e-6f);
    float m = fmaxf(amax * r, 1e-5f);
    float s = 127.f / m;
    int q0 = quant8((v0 * r) * s);
    int q1 = quant8((v1 * r) * s);
    int q2 = quant8((v2 * r) * s);
    int q3 = quant8((v3 * r) * s);
    int packed = (q0 & 0xff) | ((q1 & 0xff) << 8) | ((q2 & 0xff) << 16) | ((q3 & 0xff) << 24);
    ((int*)(X8 + (size_t)row * 1024))[t] = packed;
    if (t == 0) RS[row] = m * (1.f / 127.f);
}

// ------------------------------------------------------------------ GEMM ----
// C[M,N] = A[M,K](int8) . B[N,K](int8 ternary)^T, dequant by rowscale*beta.
// 128x128 block tile, BK=64, mfma_i32_16x16x64_i8, 4 waves -> 64x64 each.
__global__ __launch_bounds__(256) void gemm_i8(
    const signed char* __restrict__ A, const signed char* __restrict__ B,
    float* __restrict__ outp, int N, int K,
    const float* __restrict__ rowscale, const float* __restrict__ betas,
    int b0i, int b1i, int split, float extra)
{
    __shared__ __align__(16) signed char As[128 * 80];
    __shared__ __align__(16) signed char Bs[128 * 80];
    const int tid = threadIdx.x;
    const int lane = tid & 63, wid = tid >> 6;
    const int wr = wid >> 1, wc = wid & 1;
    const int lr = lane & 15, quad = lane >> 4;
    const int bM = blockIdx.y, bN = blockIdx.x;
    const int r0 = tid >> 2, o0 = (tid & 3) * 16;

    int4v zero = {0, 0, 0, 0};
    int4v acc[4][4];
    #pragma unroll
    for (int i = 0; i < 4; i++)
        #pragma unroll
        for (int j = 0; j < 4; j++) acc[i][j] = zero;

    const signed char* Ab = A + (size_t)(bM * 128 + r0) * K + o0;
    const signed char* Bb = B + (size_t)(bN * 128 + r0) * K + o0;

    for (int kb = 0; kb < K; kb += 64) {
        int4v a0 = *(const int4v*)(Ab + kb);
        int4v a1 = *(const int4v*)(Ab + (size_t)64 * K + kb);
        int4v bv0 = *(const int4v*)(Bb + kb);
        int4v bv1 = *(const int4v*)(Bb + (size_t)64 * K + kb);
        __syncthreads();
        *(int4v*)(As + r0 * 80 + o0) = a0;
        *(int4v*)(As + (r0 + 64) * 80 + o0) = a1;
        *(int4v*)(Bs + r0 * 80 + o0) = bv0;
        *(int4v*)(Bs + (r0 + 64) * 80 + o0) = bv1;
        __syncthreads();
        int4v af[4], bfr[4];
        #pragma unroll
        for (int tm = 0; tm < 4; tm++)
            af[tm] = *(const int4v*)(As + (wr * 64 + tm * 16 + lr) * 80 + quad * 16);
        #pragma unroll
        for (int tn = 0; tn < 4; tn++)
            bfr[tn] = *(const int4v*)(Bs + (wc * 64 + tn * 16 + lr) * 80 + quad * 16);
        #pragma unroll
        for (int tm = 0; tm < 4; tm++)
            #pragma unroll
            for (int tn = 0; tn < 4; tn++)
                acc[tm][tn] = __builtin_amdgcn_mfma_i32_16x16x64_i8(af[tm], bfr[tn], acc[tm][tn], 0, 0, 0);
    }

    const float s0 = betas[b0i] * extra, s1 = betas[b1i] * extra;
    #pragma unroll
    for (int tm = 0; tm < 4; tm++) {
        #pragma unroll
        for (int r = 0; r < 4; r++) {
            int grow = bM * 128 + wr * 64 + tm * 16 + quad * 4 + r;
            float rs = rowscale[grow];
            #pragma unroll
            for (int tn = 0; tn < 4; tn++) {
                int col = bN * 128 + wc * 64 + tn * 16 + lr;
                float v = (float)acc[tm][tn][r] * rs * (col < split ? s0 : s1);
                outp[(size_t)grow * N + col] = v;
            }
        }
    }
}

// -------------------------------------------------------------- attention ---
// One wave = 64 queries (one per lane) for a fixed (b,h,g). K/V rows are
// wave-uniform -> broadcast loads. Two-pass online softmax. Runs IN-PLACE:
// each wave reads q columns (h*2+g)*64..+63 of its own 64 rows into registers
// up front and writes the attention output back to the same slice (no other
// wave touches that slice), so Q and O may alias.
__global__ __launch_bounds__(256) void attn_kernel(
    const float* Q, const float* KV, float* O)
{
    int tid = threadIdx.x;
    int lane = tid & 63;
    int wid = __builtin_amdgcn_readfirstlane(tid >> 6);
    int W = blockIdx.x * 4 + wid;
    int ng = W & 15, g = (W >> 4) & 1, h = (W >> 5) & 7, b = W >> 8;
    int qrow = b * 1024 + ng * 64 + lane;
    const float* qp = Q + (size_t)qrow * 1024 + (h * 2 + g) * 64;
    float4 q[16];
    #pragma unroll
    for (int e = 0; e < 16; e++) q[e] = *(const float4*)(qp + 4 * e);

    const float* kb = KV + (size_t)b * 256 * 1024 + h * 64;
    const float* vb = kb + 512;

    float m = -3.402823466e38f, l = 0.f;
    for (int s = 0; s < 256; s++) {
        const float* kr = kb + (size_t)s * 1024;
        float a0 = 0.f, a1 = 0.f, a2 = 0.f, a3 = 0.f;
        #pragma unroll
        for (int e = 0; e < 16; e++) {
            float4 kv = *(const float4*)(kr + 4 * e);
            a0 = fmaf(q[e].x, kv.x, a0);
            a1 = fmaf(q[e].y, kv.y, a1);
            a2 = fmaf(q[e].z, kv.z, a2);
            a3 = fmaf(q[e].w, kv.w, a3);
        }
        float acc = (a0 + a1) + (a2 + a3);
        float nm = fmaxf(m, acc);
        l = l * __expf(m - nm) + __expf(acc - nm);
        m = nm;
    }
    float linv = 1.f / l;

    float4 o[16];
    #pragma unroll
    for (int e = 0; e < 16; e++) { o[e].x = 0.f; o[e].y = 0.f; o[e].z = 0.f; o[e].w = 0.f; }

    for (int s = 0; s < 256; s++) {
        const float* kr = kb + (size_t)s * 1024;
        float a0 = 0.f, a1 = 0.f, a2 = 0.f, a3 = 0.f;
        #pragma unroll
        for (int e = 0; e < 16; e++) {
            float4 kv = *(const float4*)(kr + 4 * e);
            a0 = fmaf(q[e].x, kv.x, a0);
            a1 = fmaf(q[e].y, kv.y, a1);
            a2 = fmaf(q[e].z, kv.z, a2);
            a3 = fmaf(q[e].w, kv.w, a3);
        }
        float acc = (a0 + a1) + (a2 + a3);
        float p = __expf(acc - m) * linv;
        const float* vr = vb + (size_t)s * 1024;
        #pragma unroll
        for (int e = 0; e < 16; e++) {
            float4 vv = *(const float4*)(vr + 4 * e);
            o[e].x = fmaf(p, vv.x, o[e].x);
            o[e].y = fmaf(p, vv.y, o[e].y);
            o[e].z = fmaf(p, vv.z, o[e].z);
            o[e].w = fmaf(p, vv.w, o[e].w);
        }
    }

    float* op = O + (size_t)qrow * 1024 + (h * 2 + g) * 64;
    #pragma unroll
    for (int e = 0; e < 16; e++) *(float4*)(op + 4 * e) = o[e];
}

// ---------------------------------------------------- LayerNorm + re-quant ---
// LN(gamma,beta) over D=1024, then rms_norm + int8 act quant for out proj.
__global__ __launch_bounds__(256) void ln_quant(
    const float* __restrict__ AO, const float* __restrict__ G,
    const float* __restrict__ Bt, signed char* __restrict__ O8,
    float* __restrict__ OS)
{
    __shared__ float red[256];
    int row = blockIdx.x, t = threadIdx.x;
    float4 x = ((const float4*)(AO + (size_t)row * 1024))[t];
    float mu = blk_sum(x.x + x.y + x.z + x.w, red) * (1.f / 1024.f);
    float d0 = x.x - mu, d1 = x.y - mu, d2 = x.z - mu, d3 = x.w - mu;
    float var = blk_sum(d0 * d0 + d1 * d1 + d2 * d2 + d3 * d3, red) * (1.f / 1024.f);
    float rstd = 1.f / sqrtf(var + 1e-5f);
    float4 gu = ((const float4*)G)[t];
    float4 bu = ((const float4*)Bt)[t];
    float l0 = d0 * rstd * gu.x + bu.x;
    float l1 = d1 * rstd * gu.y + bu.y;
    float l2 = d2 * rstd * gu.z + bu.z;
    float l3 = d3 * rstd * gu.w + bu.w;
    float msq = blk_sum(l0 * l0 + l1 * l1 + l2 * l2 + l3 * l3, red) * (1.f / 1024.f);
    float am = fmaxf(fmaxf(fabsf(l0), fabsf(l1)), fmaxf(fabsf(l2), fabsf(l3)));
    float amax = blk_max(am, red);
    float r2 = 1.f / sqrtf(msq + 1e-6f);
    float mx = fmaxf(amax * r2, 1e-5f);
    float s = 127.f / mx;
    int q0 = quant8((l0 * r2) * s);
    int q1 = quant8((l1 * r2) * s);
    int q2 = quant8((l2 * r2) * s);
    int q3 = quant8((l3 * r2) * s);
    int packed = (q0 & 0xff) | ((q1 & 0xff) << 8) | ((q2 & 0xff) << 16) | ((q3 & 0xff) << 24);
    ((int*)(O8 + (size_t)row * 1024))[t] = packed;
    if (t == 0) OS[row] = mx * (1.f / 127.f);
}

// ------------------------------------------------------------------ launch ---
extern "C" void kernel_launch(void* const* d_in, const int* in_sizes, int n_in,
                              void* d_out, int out_size, void* d_ws, size_t ws_size,
                              hipStream_t stream)
{
    const float* X  = (const float*)d_in[0];
    const float* Y  = (const float*)d_in[1];
    const float* WQ = (const float*)d_in[2];
    const float* WK = (const float*)d_in[3];
    const float* WV = (const float*)d_in[4];
    const float* WO = (const float*)d_in[5];
    const float* G  = (const float*)d_in[6];
    const float* Bt = (const float*)d_in[7];

    // workspace layout (~103 MB total)
    char* ws = (char*)d_ws;
    float*  betas = (float*)ws;                    // 16 B
    double* part  = (double*)(ws + 256);           // 2 KB
    char* wq8 = ws + 4096;                         // 1 MB
    char* kv8 = wq8 + (1 << 20);                   // 1 MB (wk rows 0-511, wv rows 512-1023)
    char* wo8 = kv8 + (1 << 20);                   // 1 MB
    char* x8  = wo8 + (1 << 20);                   // 16 MB (reused as o8 after q-gemm)
    char* y8  = x8 + (16 << 20);                   // 4 MB
    float* xs = (float*)(y8 + (4 << 20));          // 64 KB
    float* ys = xs + 16384;                        // 16 KB
    float* os = ys + 4096;                         // 64 KB
    float* qf  = os + 16384;                       // 64 MB (16384x1024 f32; attn output in-place)
    float* kvf = qf + (size_t)16384 * 1024;        // 16 MB (4096x1024 f32)
    char*  o8  = x8;                               // alias: x8 dead after q projection

    absmean_partial<<<64, 256, 0, stream>>>(WQ, part + 0,   16384);
    absmean_partial<<<64, 256, 0, stream>>>(WK, part + 64,  8192);
    absmean_partial<<<64, 256, 0, stream>>>(WV, part + 128, 8192);
    absmean_partial<<<64, 256, 0, stream>>>(WO, part + 192, 16384);
    betas_kernel<<<1, 256, 0, stream>>>(part, betas);

    wquant<<<1024, 256, 0, stream>>>(WQ, (signed char*)wq8, betas, 0);
    wquant<<<512,  256, 0, stream>>>(WK, (signed char*)kv8, betas, 1);
    wquant<<<512,  256, 0, stream>>>(WV, (signed char*)(kv8 + 512 * 1024), betas, 2);
    wquant<<<1024, 256, 0, stream>>>(WO, (signed char*)wo8, betas, 3);

    act_quant<<<16384, 256, 0, stream>>>(X, (signed char*)x8, xs);
    act_quant<<<4096,  256, 0, stream>>>(Y, (signed char*)y8, ys);

    // q projection (scale 1/sqrt(64) folded into epilogue)
    gemm_i8<<<dim3(8, 128), 256, 0, stream>>>((signed char*)x8, (signed char*)wq8, qf,
                                              1024, 1024, xs, betas, 0, 0, 1024, 0.125f);
    // fused k|v projection: cols 0-511 use beta_k, 512-1023 use beta_v
    gemm_i8<<<dim3(8, 32), 256, 0, stream>>>((signed char*)y8, (signed char*)kv8, kvf,
                                             1024, 1024, ys, betas, 1, 2, 512, 1.f);

    // grouped-query attention, in-place on qf
    attn_kernel<<<1024, 256, 0, stream>>>(qf, kvf, qf);

    ln_quant<<<16384, 256, 0, stream>>>(qf, G, Bt, (signed char*)o8, os);

    // out projection, f32 output
    gemm_i8<<<dim3(8, 128), 256, 0, stream>>>((signed char*)o8, (signed char*)wo8, (float*)d_out,
                                              1024, 1024, os, betas, 3, 3, 1024, 1.f);
}

// Round 3
// 467.448 us; speedup vs baseline: 2.1060x; 2.1060x over previous
//
#include <hip/hip_runtime.h>
#include <hip/hip_bf16.h>

typedef int int4v __attribute__((ext_vector_type(4)));
typedef float float4v __attribute__((ext_vector_type(4)));
typedef _Float16 half8 __attribute__((ext_vector_type(8)));
typedef _Float16 half4 __attribute__((ext_vector_type(4)));

#define DEV __device__ __forceinline__

DEV signed char quant8(float v) {
    int q = (int)rintf(v);
    q = q < -128 ? -128 : (q > 127 ? 127 : q);
    return (signed char)q;
}

DEV int tern1(float v) {
    int q = (int)rintf(v);
    q = q < -1 ? -1 : (q > 1 ? 1 : q);
    return q;
}

DEV float blk_sum(float v, float* red) {
    int t = threadIdx.x;
    red[t] = v; __syncthreads();
    #pragma unroll
    for (int o = 128; o > 0; o >>= 1) {
        if (t < o) red[t] += red[t + o];
        __syncthreads();
    }
    float r = red[0]; __syncthreads();
    return r;
}

DEV float blk_max(float v, float* red) {
    int t = threadIdx.x;
    red[t] = v; __syncthreads();
    #pragma unroll
    for (int o = 128; o > 0; o >>= 1) {
        if (t < o) red[t] = fmaxf(red[t], red[t + o]);
        __syncthreads();
    }
    float r = red[0]; __syncthreads();
    return r;
}

// ---------------------------------------------------------------- weights ---
__global__ __launch_bounds__(256) void absmean_partial(
    const float* __restrict__ W, double* __restrict__ part, int nper)
{
    __shared__ double red[256];
    int t = threadIdx.x;
    size_t base = (size_t)blockIdx.x * nper;
    double acc = 0.0;
    for (int i = t; i < nper; i += 256) acc += (double)fabsf(W[base + i]);
    red[t] = acc; __syncthreads();
    #pragma unroll
    for (int o = 128; o > 0; o >>= 1) {
        if (t < o) red[t] += red[t + o];
        __syncthreads();
    }
    if (t == 0) part[blockIdx.x] = red[0];
}

__global__ __launch_bounds__(256) void betas_kernel(
    const double* __restrict__ part, float* __restrict__ betas)
{
    int t = threadIdx.x, w = t >> 6, lane = t & 63;
    const int counts[4] = {1048576, 524288, 524288, 1048576};
    double v = part[w * 64 + lane];
    #pragma unroll
    for (int o = 32; o > 0; o >>= 1) v += __shfl_down(v, o);
    if (lane == 0) betas[w] = fmaxf((float)(v / (double)counts[w]), 1e-5f);
}

__global__ __launch_bounds__(256) void wquant(
    const float* __restrict__ W, signed char* __restrict__ O,
    const float* __restrict__ betas, int mi)
{
    int i = blockIdx.x * 256 + threadIdx.x;
    float inv = 1.f / betas[mi];
    float4 u = ((const float4*)W)[i];
    int q0 = tern1(u.x * inv);
    int q1 = tern1(u.y * inv);
    int q2 = tern1(u.z * inv);
    int q3 = tern1(u.w * inv);
    int packed = (q0 & 0xff) | ((q1 & 0xff) << 8) | ((q2 & 0xff) << 16) | ((q3 & 0xff) << 24);
    ((int*)O)[i] = packed;
}

// ------------------------------------------------------------ activations ---
__global__ __launch_bounds__(256) void act_quant(
    const float* __restrict__ X, signed char* __restrict__ X8,
    float* __restrict__ RS)
{
    __shared__ float red[256];
    int row = blockIdx.x, t = threadIdx.x;
    const float* xr = X + (size_t)row * 1024;
    float4 u = ((const float4*)xr)[t];
    float v0 = u.x, v1 = u.y, v2 = u.z, v3 = u.w;
    float ss = v0 * v0 + v1 * v1 + v2 * v2 + v3 * v3;
    float am = fmaxf(fmaxf(fabsf(v0), fabsf(v1)), fmaxf(fabsf(v2), fabsf(v3)));
    float tot = blk_sum(ss, red);
    float amax = blk_max(am, red);
    float r = 1.f / sqrtf(tot * (1.f / 1024.f) + 1e-6f);
    float m = fmaxf(amax * r, 1e-5f);
    float s = 127.f / m;
    int q0 = quant8((v0 * r) * s);
    int q1 = quant8((v1 * r) * s);
    int q2 = quant8((v2 * r) * s);
    int q3 = quant8((v3 * r) * s);
    int packed = (q0 & 0xff) | ((q1 & 0xff) << 8) | ((q2 & 0xff) << 16) | ((q3 & 0xff) << 24);
    ((int*)(X8 + (size_t)row * 1024))[t] = packed;
    if (t == 0) RS[row] = m * (1.f / 127.f);
}

// ------------------------------------------------------------------ GEMM ----
__global__ __launch_bounds__(256) void gemm_i8(
    const signed char* __restrict__ A, const signed char* __restrict__ B,
    float* __restrict__ outp, int N, int K,
    const float* __restrict__ rowscale, const float* __restrict__ betas,
    int b0i, int b1i, int split, float extra)
{
    __shared__ __align__(16) signed char As[128 * 80];
    __shared__ __align__(16) signed char Bs[128 * 80];
    const int tid = threadIdx.x;
    const int lane = tid & 63, wid = tid >> 6;
    const int wr = wid >> 1, wc = wid & 1;
    const int lr = lane & 15, quad = lane >> 4;
    const int bM = blockIdx.y, bN = blockIdx.x;
    const int r0 = tid >> 2, o0 = (tid & 3) * 16;

    int4v zero = {0, 0, 0, 0};
    int4v acc[4][4];
    #pragma unroll
    for (int i = 0; i < 4; i++)
        #pragma unroll
        for (int j = 0; j < 4; j++) acc[i][j] = zero;

    const signed char* Ab = A + (size_t)(bM * 128 + r0) * K + o0;
    const signed char* Bb = B + (size_t)(bN * 128 + r0) * K + o0;

    for (int kb = 0; kb < K; kb += 64) {
        int4v a0 = *(const int4v*)(Ab + kb);
        int4v a1 = *(const int4v*)(Ab + (size_t)64 * K + kb);
        int4v bv0 = *(const int4v*)(Bb + kb);
        int4v bv1 = *(const int4v*)(Bb + (size_t)64 * K + kb);
        __syncthreads();
        *(int4v*)(As + r0 * 80 + o0) = a0;
        *(int4v*)(As + (r0 + 64) * 80 + o0) = a1;
        *(int4v*)(Bs + r0 * 80 + o0) = bv0;
        *(int4v*)(Bs + (r0 + 64) * 80 + o0) = bv1;
        __syncthreads();
        int4v af[4], bfr[4];
        #pragma unroll
        for (int tm = 0; tm < 4; tm++)
            af[tm] = *(const int4v*)(As + (wr * 64 + tm * 16 + lr) * 80 + quad * 16);
        #pragma unroll
        for (int tn = 0; tn < 4; tn++)
            bfr[tn] = *(const int4v*)(Bs + (wc * 64 + tn * 16 + lr) * 80 + quad * 16);
        #pragma unroll
        for (int tm = 0; tm < 4; tm++)
            #pragma unroll
            for (int tn = 0; tn < 4; tn++)
                acc[tm][tn] = __builtin_amdgcn_mfma_i32_16x16x64_i8(af[tm], bfr[tn], acc[tm][tn], 0, 0, 0);
    }

    const float s0 = betas[b0i] * extra, s1 = betas[b1i] * extra;
    #pragma unroll
    for (int tm = 0; tm < 4; tm++) {
        #pragma unroll
        for (int r = 0; r < 4; r++) {
            int grow = bM * 128 + wr * 64 + tm * 16 + quad * 4 + r;
            float rs = rowscale[grow];
            #pragma unroll
            for (int tn = 0; tn < 4; tn++) {
                int col = bN * 128 + wc * 64 + tn * 16 + lr;
                float v = (float)acc[tm][tn][r] * rs * (col < split ? s0 : s1);
                outp[(size_t)grow * N + col] = v;
            }
        }
    }
}

// -------------------------------------------------------------- attention ---
// MFMA flash-style GQA. Workgroup = 4 waves; wave = 16 query rows of one
// (b,h,g). Full S=256 scores in registers (two K-tiles of 128 through LDS),
// exact full-row softmax, then PV in two halves with P round-tripped through
// per-wave LDS (C-layout -> A-layout) and V staged transposed as f16.
// In-place on Q: each wave reads only its own 16x64 slice into registers
// before any write.
__global__ __launch_bounds__(256) void attn_mfma(
    const float* Q, const float* KV, float* O)
{
    // region A: K-tile [128][72] f16 (9216) reused as Vt [64][136] f16 (8704)
    __shared__ __align__(16) _Float16 Am[9216];
    // P: per-wave [16][136] f16
    __shared__ __align__(16) _Float16 Pm[4 * 16 * 136];

    const int tid = threadIdx.x;
    const int lane = tid & 63;
    const int w = tid >> 6;          // wave id 0..3
    const int lq = lane & 15;        // fragment row/col index
    const int quad = lane >> 4;

    const int bx = blockIdx.x;       // 4096 = b(16) x h(8) x g(2) x nt(16)
    const int nt = bx & 15, g = (bx >> 4) & 1, h = (bx >> 5) & 7, b = bx >> 8;
    const int rbase = b * 1024 + nt * 64 + w * 16;   // global q row of this wave
    const int qcol0 = (h * 2 + g) * 64;

    // ---- Q fragments (A-layout): A[m=lq][k=ks*32+quad*8+j]
    half8 aq[2];
    #pragma unroll
    for (int ks = 0; ks < 2; ks++) {
        const float* qp = Q + (size_t)(rbase + lq) * 1024 + qcol0 + ks * 32 + quad * 8;
        float4 f0 = *(const float4*)qp;
        float4 f1 = *(const float4*)(qp + 4);
        aq[ks][0] = (_Float16)f0.x; aq[ks][1] = (_Float16)f0.y;
        aq[ks][2] = (_Float16)f0.z; aq[ks][3] = (_Float16)f0.w;
        aq[ks][4] = (_Float16)f1.x; aq[ks][5] = (_Float16)f1.y;
        aq[ks][6] = (_Float16)f1.z; aq[ks][7] = (_Float16)f1.w;
    }

    const float* Kg = KV + (size_t)b * 256 * 1024 + h * 64;  // [s][d] slice
    const float* Vg = Kg + 512;

    float4v acc[16];                 // S: acc[t][r] = S(row=quad*4+r, s=t*16+lq)
    float4v zf = {0.f, 0.f, 0.f, 0.f};
    #pragma unroll
    for (int t = 0; t < 16; t++) acc[t] = zf;

    // ---- QK^T over two 128-row K tiles
    #pragma unroll
    for (int half_ = 0; half_ < 2; half_++) {
        int s0 = half_ * 128;
        if (half_ > 0) __syncthreads();            // protect region A reuse
        // stage K tile: [128][64] f32 -> Am[row*72+col] f16 (flat float4 copy)
        #pragma unroll
        for (int i = 0; i < 8; i++) {
            int f = tid + 256 * i;
            int row = f >> 4, c4 = f & 15;
            float4 kf = *(const float4*)(Kg + (size_t)(s0 + row) * 1024 + c4 * 4);
            half4 hv;
            hv[0] = (_Float16)kf.x; hv[1] = (_Float16)kf.y;
            hv[2] = (_Float16)kf.z; hv[3] = (_Float16)kf.w;
            *(half4*)&Am[row * 72 + c4 * 4] = hv;
        }
        __syncthreads();
        #pragma unroll
        for (int t = 0; t < 8; t++) {
            int tg = half_ * 8 + t;
            #pragma unroll
            for (int ks = 0; ks < 2; ks++) {
                half8 bk = *(const half8*)&Am[(t * 16 + lq) * 72 + ks * 32 + quad * 8];
                acc[tg] = __builtin_amdgcn_mfma_f32_16x16x32_f16(aq[ks], bk, acc[tg], 0, 0, 0);
            }
        }
    }

    // ---- exact full-row softmax (rows = quad*4+r; cols spread over 16 lanes)
    float mr[4], lsum[4];
    #pragma unroll
    for (int r = 0; r < 4; r++) {
        float m = acc[0][r];
        #pragma unroll
        for (int t = 1; t < 16; t++) m = fmaxf(m, acc[t][r]);
        m = fmaxf(m, __shfl_xor(m, 1));
        m = fmaxf(m, __shfl_xor(m, 2));
        m = fmaxf(m, __shfl_xor(m, 4));
        m = fmaxf(m, __shfl_xor(m, 8));
        mr[r] = m;
        float l = 0.f;
        #pragma unroll
        for (int t = 0; t < 16; t++) {
            float p = __expf(acc[t][r] - m);
            acc[t][r] = p;
            l += p;
        }
        l += __shfl_xor(l, 1);
        l += __shfl_xor(l, 2);
        l += __shfl_xor(l, 4);
        l += __shfl_xor(l, 8);
        lsum[r] = l;
    }

    // ---- PV in two S-halves
    _Float16* Pw = Pm + w * (16 * 136);
    float4v oacc[4];
    #pragma unroll
    for (int dt = 0; dt < 4; dt++) oacc[dt] = zf;

    #pragma unroll
    for (int half_ = 0; half_ < 2; half_++) {
        int s0 = half_ * 128;
        __syncthreads();                    // region A (K or previous Vt) consumed
        // stage V^T tile: Vg[s0+s][dcol] -> Am[dcol*136 + s_local] f16
        {
            int w2 = tid >> 6, dcol = tid & 63;
            const float* vg = Vg + (size_t)(s0 + w2 * 32) * 1024 + dcol;
            #pragma unroll
            for (int c = 0; c < 4; c++) {
                half8 hv;
                #pragma unroll
                for (int j = 0; j < 8; j++)
                    hv[j] = (_Float16)vg[(size_t)(c * 8 + j) * 1024];
                *(half8*)&Am[dcol * 136 + w2 * 32 + c * 8] = hv;
            }
        }
        // write P half (C-layout -> LDS row-major [16][136])
        #pragma unroll
        for (int t = 0; t < 8; t++) {
            int tg = half_ * 8 + t;
            #pragma unroll
            for (int r = 0; r < 4; r++)
                Pw[(quad * 4 + r) * 136 + t * 16 + lq] = (_Float16)acc[tg][r];
        }
        __syncthreads();
        // PV: A = P[m=lq][k], B = V^T[k=s][n=dcol]
        #pragma unroll
        for (int k2 = 0; k2 < 4; k2++) {
            half8 ap = *(const half8*)&Pw[lq * 136 + k2 * 32 + quad * 8];
            #pragma unroll
            for (int dt = 0; dt < 4; dt++) {
                half8 bv = *(const half8*)&Am[(dt * 16 + lq) * 136 + k2 * 32 + quad * 8];
                oacc[dt] = __builtin_amdgcn_mfma_f32_16x16x32_f16(ap, bv, oacc[dt], 0, 0, 0);
            }
        }
    }

    // ---- epilogue: scale by 1/l, write (C-layout rows match lsum mapping)
    float inv[4];
    #pragma unroll
    for (int r = 0; r < 4; r++) inv[r] = 1.f / lsum[r];
    #pragma unroll
    for (int dt = 0; dt < 4; dt++) {
        #pragma unroll
        for (int r = 0; r < 4; r++) {
            O[(size_t)(rbase + quad * 4 + r) * 1024 + qcol0 + dt * 16 + lq] =
                oacc[dt][r] * inv[r];
        }
    }
}

// ---------------------------------------------------- LayerNorm + re-quant ---
__global__ __launch_bounds__(256) void ln_quant(
    const float* __restrict__ AO, const float* __restrict__ G,
    const float* __restrict__ Bt, signed char* __restrict__ O8,
    float* __restrict__ OS)
{
    __shared__ float red[256];
    int row = blockIdx.x, t = threadIdx.x;
    float4 x = ((const float4*)(AO + (size_t)row * 1024))[t];
    float mu = blk_sum(x.x + x.y + x.z + x.w, red) * (1.f / 1024.f);
    float d0 = x.x - mu, d1 = x.y - mu, d2 = x.z - mu, d3 = x.w - mu;
    float var = blk_sum(d0 * d0 + d1 * d1 + d2 * d2 + d3 * d3, red) * (1.f / 1024.f);
    float rstd = 1.f / sqrtf(var + 1e-5f);
    float4 gu = ((const float4*)G)[t];
    float4 bu = ((const float4*)Bt)[t];
    float l0 = d0 * rstd * gu.x + bu.x;
    float l1 = d1 * rstd * gu.y + bu.y;
    float l2 = d2 * rstd * gu.z + bu.z;
    float l3 = d3 * rstd * gu.w + bu.w;
    float msq = blk_sum(l0 * l0 + l1 * l1 + l2 * l2 + l3 * l3, red) * (1.f / 1024.f);
    float am = fmaxf(fmaxf(fabsf(l0), fabsf(l1)), fmaxf(fabsf(l2), fabsf(l3)));
    float amax = blk_max(am, red);
    float r2 = 1.f / sqrtf(msq + 1e-6f);
    float mx = fmaxf(amax * r2, 1e-5f);
    float s = 127.f / mx;
    int q0 = quant8((l0 * r2) * s);
    int q1 = quant8((l1 * r2) * s);
    int q2 = quant8((l2 * r2) * s);
    int q3 = quant8((l3 * r2) * s);
    int packed = (q0 & 0xff) | ((q1 & 0xff) << 8) | ((q2 & 0xff) << 16) | ((q3 & 0xff) << 24);
    ((int*)(O8 + (size_t)row * 1024))[t] = packed;
    if (t == 0) OS[row] = mx * (1.f / 127.f);
}

// ------------------------------------------------------------------ launch ---
extern "C" void kernel_launch(void* const* d_in, const int* in_sizes, int n_in,
                              void* d_out, int out_size, void* d_ws, size_t ws_size,
                              hipStream_t stream)
{
    const float* X  = (const float*)d_in[0];
    const float* Y  = (const float*)d_in[1];
    const float* WQ = (const float*)d_in[2];
    const float* WK = (const float*)d_in[3];
    const float* WV = (const float*)d_in[4];
    const float* WO = (const float*)d_in[5];
    const float* G  = (const float*)d_in[6];
    const float* Bt = (const float*)d_in[7];

    char* ws = (char*)d_ws;
    float*  betas = (float*)ws;                    // 16 B
    double* part  = (double*)(ws + 256);           // 2 KB
    char* wq8 = ws + 4096;                         // 1 MB
    char* kv8 = wq8 + (1 << 20);                   // 1 MB
    char* wo8 = kv8 + (1 << 20);                   // 1 MB
    char* x8  = wo8 + (1 << 20);                   // 16 MB (reused as o8)
    char* y8  = x8 + (16 << 20);                   // 4 MB
    float* xs = (float*)(y8 + (4 << 20));          // 64 KB
    float* ys = xs + 16384;                        // 16 KB
    float* os = ys + 4096;                         // 64 KB
    float* qf  = os + 16384;                       // 64 MB (attn in-place)
    float* kvf = qf + (size_t)16384 * 1024;        // 16 MB
    char*  o8  = x8;

    absmean_partial<<<64, 256, 0, stream>>>(WQ, part + 0,   16384);
    absmean_partial<<<64, 256, 0, stream>>>(WK, part + 64,  8192);
    absmean_partial<<<64, 256, 0, stream>>>(WV, part + 128, 8192);
    absmean_partial<<<64, 256, 0, stream>>>(WO, part + 192, 16384);
    betas_kernel<<<1, 256, 0, stream>>>(part, betas);

    wquant<<<1024, 256, 0, stream>>>(WQ, (signed char*)wq8, betas, 0);
    wquant<<<512,  256, 0, stream>>>(WK, (signed char*)kv8, betas, 1);
    wquant<<<512,  256, 0, stream>>>(WV, (signed char*)(kv8 + 512 * 1024), betas, 2);
    wquant<<<1024, 256, 0, stream>>>(WO, (signed char*)wo8, betas, 3);

    act_quant<<<16384, 256, 0, stream>>>(X, (signed char*)x8, xs);
    act_quant<<<4096,  256, 0, stream>>>(Y, (signed char*)y8, ys);

    gemm_i8<<<dim3(8, 128), 256, 0, stream>>>((signed char*)x8, (signed char*)wq8, qf,
                                              1024, 1024, xs, betas, 0, 0, 1024, 0.125f);
    gemm_i8<<<dim3(8, 32), 256, 0, stream>>>((signed char*)y8, (signed char*)kv8, kvf,
                                             1024, 1024, ys, betas, 1, 2, 512, 1.f);

    attn_mfma<<<4096, 256, 0, stream>>>(qf, kvf, qf);

    ln_quant<<<16384, 256, 0, stream>>>(qf, G, Bt, (signed char*)o8, os);

    gemm_i8<<<dim3(8, 128), 256, 0, stream>>>((signed char*)o8, (signed char*)wo8, (float*)d_out,
                                              1024, 1024, os, betas, 3, 3, 1024, 1.f);
}

// Round 4
// 449.872 us; speedup vs baseline: 2.1883x; 1.0391x over previous
//
#include <hip/hip_runtime.h>
#include <hip/hip_bf16.h>

typedef int int4v __attribute__((ext_vector_type(4)));
typedef float float4v __attribute__((ext_vector_type(4)));
typedef _Float16 half8 __attribute__((ext_vector_type(8)));

#define DEV __device__ __forceinline__

DEV signed char quant8(float v) {
    int q = (int)rintf(v);
    q = q < -128 ? -128 : (q > 127 ? 127 : q);
    return (signed char)q;
}

DEV int tern1(float v) {
    int q = (int)rintf(v);
    q = q < -1 ? -1 : (q > 1 ? 1 : q);
    return q;
}

// ---------------------------------------------------------------- weights ---
// One launch: 192 blocks -> per-block partial |w| sums (double).
// blocks [0,64)=WQ [64,96)=WK [96,128)=WV [128,192)=WO, 16384 elems each.
__global__ __launch_bounds__(256) void absmean_all(
    const float* __restrict__ WQ, const float* __restrict__ WK,
    const float* __restrict__ WV, const float* __restrict__ WO,
    double* __restrict__ part)
{
    __shared__ double red[256];
    int bx = blockIdx.x, t = threadIdx.x;
    const float* W; int rel;
    if (bx < 64)       { W = WQ; rel = bx; }
    else if (bx < 96)  { W = WK; rel = bx - 64; }
    else if (bx < 128) { W = WV; rel = bx - 96; }
    else               { W = WO; rel = bx - 128; }
    size_t base = (size_t)rel * 16384;
    double acc = 0.0;
    for (int i = t; i < 16384; i += 256) acc += (double)fabsf(W[base + i]);
    red[t] = acc; __syncthreads();
    #pragma unroll
    for (int o = 128; o > 0; o >>= 1) {
        if (t < o) red[t] += red[t + o];
        __syncthreads();
    }
    if (t == 0) part[bx] = red[0];
}

// wave w reduces its matrix's partials -> beta = max(mean,1e-5)
__global__ __launch_bounds__(256) void betas_kernel(
    const double* __restrict__ part, float* __restrict__ betas)
{
    int t = threadIdx.x, w = t >> 6, lane = t & 63;
    const int offs[4]   = {0, 64, 96, 128};
    const int cnts[4]   = {64, 32, 32, 64};
    const int counts[4] = {1048576, 524288, 524288, 1048576};
    double v = (lane < cnts[w]) ? part[offs[w] + lane] : 0.0;
    #pragma unroll
    for (int o = 32; o > 0; o >>= 1) v += __shfl_down(v, o);
    if (lane == 0) betas[w] = fmaxf((float)(v / (double)counts[w]), 1e-5f);
}

// One launch: ternary-quantize all four weight matrices into w8 region.
__global__ __launch_bounds__(256) void wquant_all(
    const float* __restrict__ WQ, const float* __restrict__ WK,
    const float* __restrict__ WV, const float* __restrict__ WO,
    signed char* __restrict__ w8, const float* __restrict__ betas)
{
    int bx = blockIdx.x;
    const float* W; signed char* O; float inv; int rel;
    if (bx < 1024)      { W = WQ; O = w8;                         rel = bx;        inv = 1.f / betas[0]; }
    else if (bx < 1536) { W = WK; O = w8 + (1 << 20);             rel = bx - 1024; inv = 1.f / betas[1]; }
    else if (bx < 2048) { W = WV; O = w8 + (1 << 20) + (512 << 10); rel = bx - 1536; inv = 1.f / betas[2]; }
    else                { W = WO; O = w8 + (2 << 20);             rel = bx - 2048; inv = 1.f / betas[3]; }
    int i = rel * 256 + threadIdx.x;
    float4 u = ((const float4*)W)[i];
    int q0 = tern1(u.x * inv);
    int q1 = tern1(u.y * inv);
    int q2 = tern1(u.z * inv);
    int q3 = tern1(u.w * inv);
    int packed = (q0 & 0xff) | ((q1 & 0xff) << 8) | ((q2 & 0xff) << 16) | ((q3 & 0xff) << 24);
    ((int*)O)[i] = packed;
}

// ------------------------------------------------------------ activations ---
// Wave-per-row (4 rows/block), shuffle butterflies, zero barriers.
__global__ __launch_bounds__(256) void act_quant(
    const float* __restrict__ X, signed char* __restrict__ X8,
    float* __restrict__ RS)
{
    int row = blockIdx.x * 4 + (threadIdx.x >> 6);
    int lane = threadIdx.x & 63;
    const float4* xr = (const float4*)(X + (size_t)row * 1024) + lane * 4;
    float4 u[4];
    #pragma unroll
    for (int i = 0; i < 4; i++) u[i] = xr[i];
    float ss = 0.f, am = 0.f;
    #pragma unroll
    for (int i = 0; i < 4; i++) {
        ss += u[i].x * u[i].x + u[i].y * u[i].y + u[i].z * u[i].z + u[i].w * u[i].w;
        am = fmaxf(am, fmaxf(fmaxf(fabsf(u[i].x), fabsf(u[i].y)),
                             fmaxf(fabsf(u[i].z), fabsf(u[i].w))));
    }
    #pragma unroll
    for (int o = 32; o > 0; o >>= 1) {
        ss += __shfl_xor(ss, o);
        am = fmaxf(am, __shfl_xor(am, o));
    }
    float r = 1.f / sqrtf(ss * (1.f / 1024.f) + 1e-6f);
    float m = fmaxf(am * r, 1e-5f);
    float s = 127.f / m;
    int pk[4];
    #pragma unroll
    for (int i = 0; i < 4; i++) {
        int q0 = quant8((u[i].x * r) * s);
        int q1 = quant8((u[i].y * r) * s);
        int q2 = quant8((u[i].z * r) * s);
        int q3 = quant8((u[i].w * r) * s);
        pk[i] = (q0 & 0xff) | ((q1 & 0xff) << 8) | ((q2 & 0xff) << 16) | ((q3 & 0xff) << 24);
    }
    int4v pv = {pk[0], pk[1], pk[2], pk[3]};
    ((int4v*)(X8 + (size_t)row * 1024))[lane] = pv;
    if (lane == 0) RS[row] = m * (1.f / 127.f);
}

// ------------------------------------------------------------------ GEMM ----
// C[M,N] = A[M,K](int8) . B[N,K](int8 ternary)^T, dequant rowscale*beta.
// mode 0: f32 out  mode 1: f16 out (q)  mode 2: k->kf16 / v->vt16 transposed
__global__ __launch_bounds__(256) void gemm_i8(
    const signed char* __restrict__ A, const signed char* __restrict__ B,
    float* __restrict__ outF, _Float16* __restrict__ outH,
    _Float16* __restrict__ outK, _Float16* __restrict__ outV,
    int N, int K,
    const float* __restrict__ rowscale, const float* __restrict__ betas,
    int b0i, int b1i, int split, float extra, int mode)
{
    __shared__ __align__(16) signed char As[128 * 80];
    __shared__ __align__(16) signed char Bs[128 * 80];
    const int tid = threadIdx.x;
    const int lane = tid & 63, wid = tid >> 6;
    const int wr = wid >> 1, wc = wid & 1;
    const int lr = lane & 15, quad = lane >> 4;
    const int bM = blockIdx.y, bN = blockIdx.x;
    const int r0 = tid >> 2, o0 = (tid & 3) * 16;

    int4v zero = {0, 0, 0, 0};
    int4v acc[4][4];
    #pragma unroll
    for (int i = 0; i < 4; i++)
        #pragma unroll
        for (int j = 0; j < 4; j++) acc[i][j] = zero;

    const signed char* Ab = A + (size_t)(bM * 128 + r0) * K + o0;
    const signed char* Bb = B + (size_t)(bN * 128 + r0) * K + o0;

    for (int kb = 0; kb < K; kb += 64) {
        int4v a0 = *(const int4v*)(Ab + kb);
        int4v a1 = *(const int4v*)(Ab + (size_t)64 * K + kb);
        int4v bv0 = *(const int4v*)(Bb + kb);
        int4v bv1 = *(const int4v*)(Bb + (size_t)64 * K + kb);
        __syncthreads();
        *(int4v*)(As + r0 * 80 + o0) = a0;
        *(int4v*)(As + (r0 + 64) * 80 + o0) = a1;
        *(int4v*)(Bs + r0 * 80 + o0) = bv0;
        *(int4v*)(Bs + (r0 + 64) * 80 + o0) = bv1;
        __syncthreads();
        int4v af[4], bfr[4];
        #pragma unroll
        for (int tm = 0; tm < 4; tm++)
            af[tm] = *(const int4v*)(As + (wr * 64 + tm * 16 + lr) * 80 + quad * 16);
        #pragma unroll
        for (int tn = 0; tn < 4; tn++)
            bfr[tn] = *(const int4v*)(Bs + (wc * 64 + tn * 16 + lr) * 80 + quad * 16);
        #pragma unroll
        for (int tm = 0; tm < 4; tm++)
            #pragma unroll
            for (int tn = 0; tn < 4; tn++)
                acc[tm][tn] = __builtin_amdgcn_mfma_i32_16x16x64_i8(af[tm], bfr[tn], acc[tm][tn], 0, 0, 0);
    }

    const float s0 = betas[b0i] * extra, s1 = betas[b1i] * extra;
    #pragma unroll
    for (int tm = 0; tm < 4; tm++) {
        #pragma unroll
        for (int r = 0; r < 4; r++) {
            int grow = bM * 128 + wr * 64 + tm * 16 + quad * 4 + r;
            float rs = rowscale[grow];
            #pragma unroll
            for (int tn = 0; tn < 4; tn++) {
                int col = bN * 128 + wc * 64 + tn * 16 + lr;
                float v = (float)acc[tm][tn][r] * rs * (col < split ? s0 : s1);
                if (mode == 0) {
                    outF[(size_t)grow * N + col] = v;
                } else if (mode == 1) {
                    outH[(size_t)grow * 1024 + col] = (_Float16)v;
                } else {
                    if (col < 512)
                        outK[(size_t)grow * 512 + col] = (_Float16)v;
                    else
                        outV[((size_t)(grow >> 8) * 512 + (col - 512)) * 256 + (grow & 255)] = (_Float16)v;
                }
            }
        }
    }
}

// -------------------------------------------------------------- attention ---
// Barrier-free MFMA GQA. Wave = 16 query rows of one (b,h,g). Q/K/V read as
// f16 fragments directly from global (kf16 row-major in d, vt16 transposed
// row-major in s). Full S=256 scores in registers, exact softmax, P through
// per-wave LDS (writes 2-way/free, reads conflict-free). In-place on qf16.
__global__ __launch_bounds__(256) void attn_mfma(
    const _Float16* Qh, const _Float16* __restrict__ Kh,
    const _Float16* __restrict__ Vt, _Float16* Oh)
{
    __shared__ __align__(16) _Float16 Pm[4 * 16 * 136];   // 17408 B

    const int tid = threadIdx.x;
    const int lane = tid & 63;
    const int w = tid >> 6;
    const int lq = lane & 15;
    const int quad = lane >> 4;

    const int bx = blockIdx.x;       // b(16) x h(8) x g(2) x nt(16)
    const int nt = bx & 15, g = (bx >> 4) & 1, h = (bx >> 5) & 7, b = bx >> 8;
    const int rbase = b * 1024 + nt * 64 + w * 16;
    const int qcol0 = (h * 2 + g) * 64;

    // Q fragments (A-layout), already scaled by 1/8 in the q-gemm epilogue
    half8 aq[2];
    #pragma unroll
    for (int ks = 0; ks < 2; ks++)
        aq[ks] = *(const half8*)(Qh + (size_t)(rbase + lq) * 1024 + qcol0 + ks * 32 + quad * 8);

    // QK^T : B-fragment rows = K tokens, k-dim = head cols
    const _Float16* Kb = Kh + (size_t)b * 256 * 512 + h * 64;
    float4v acc[16];
    float4v zf = {0.f, 0.f, 0.f, 0.f};
    #pragma unroll
    for (int t = 0; t < 16; t++) acc[t] = zf;
    #pragma unroll
    for (int t = 0; t < 16; t++) {
        #pragma unroll
        for (int ks = 0; ks < 2; ks++) {
            half8 bk = *(const half8*)(Kb + (size_t)(t * 16 + lq) * 512 + ks * 32 + quad * 8);
            acc[t] = __builtin_amdgcn_mfma_f32_16x16x32_f16(aq[ks], bk, acc[t], 0, 0, 0);
        }
    }

    // exact full-row softmax (row = quad*4+r, cols spread over 16 lanes)
    float lsum[4];
    #pragma unroll
    for (int r = 0; r < 4; r++) {
        float m = acc[0][r];
        #pragma unroll
        for (int t = 1; t < 16; t++) m = fmaxf(m, acc[t][r]);
        m = fmaxf(m, __shfl_xor(m, 1));
        m = fmaxf(m, __shfl_xor(m, 2));
        m = fmaxf(m, __shfl_xor(m, 4));
        m = fmaxf(m, __shfl_xor(m, 8));
        float l = 0.f;
        #pragma unroll
        for (int t = 0; t < 16; t++) {
            float p = __expf(acc[t][r] - m);
            acc[t][r] = p;
            l += p;
        }
        l += __shfl_xor(l, 1);
        l += __shfl_xor(l, 2);
        l += __shfl_xor(l, 4);
        l += __shfl_xor(l, 8);
        lsum[r] = l;
    }

    // PV in two S-halves; P round-trips through per-wave LDS (no barriers:
    // within-wave DS ordering + compiler lgkmcnt waits suffice)
    _Float16* Pw = Pm + w * (16 * 136);
    const _Float16* Vb = Vt + ((size_t)b * 512 + h * 64) * 256;
    float4v oacc[4];
    #pragma unroll
    for (int dt = 0; dt < 4; dt++) oacc[dt] = zf;

    #pragma unroll
    for (int half_ = 0; half_ < 2; half_++) {
        #pragma unroll
        for (int t = 0; t < 8; t++) {
            int tg = half_ * 8 + t;
            #pragma unroll
            for (int r = 0; r < 4; r++)
                Pw[(quad * 4 + r) * 136 + t * 16 + lq] = (_Float16)acc[tg][r];
        }
        #pragma unroll
        for (int k2 = 0; k2 < 4; k2++) {
            half8 ap = *(const half8*)&Pw[lq * 136 + k2 * 32 + quad * 8];
            #pragma unroll
            for (int dt = 0; dt < 4; dt++) {
                half8 bv = *(const half8*)(Vb + (size_t)(dt * 16 + lq) * 256 +
                                           half_ * 128 + k2 * 32 + quad * 8);
                oacc[dt] = __builtin_amdgcn_mfma_f32_16x16x32_f16(ap, bv, oacc[dt], 0, 0, 0);
            }
        }
    }

    // epilogue: normalize, write f16 in-place
    float inv[4];
    #pragma unroll
    for (int r = 0; r < 4; r++) inv[r] = 1.f / lsum[r];
    #pragma unroll
    for (int dt = 0; dt < 4; dt++) {
        #pragma unroll
        for (int r = 0; r < 4; r++) {
            Oh[(size_t)(rbase + quad * 4 + r) * 1024 + qcol0 + dt * 16 + lq] =
                (_Float16)(oacc[dt][r] * inv[r]);
        }
    }
}

// ---------------------------------------------------- LayerNorm + re-quant ---
// Wave-per-row (4/block), f16 input, shuffle butterflies, zero barriers.
__global__ __launch_bounds__(256) void ln_quant(
    const _Float16* __restrict__ AO, const float* __restrict__ G,
    const float* __restrict__ Bt, signed char* __restrict__ O8,
    float* __restrict__ OS)
{
    int row = blockIdx.x * 4 + (threadIdx.x >> 6);
    int lane = threadIdx.x & 63;
    const _Float16* xr = AO + (size_t)row * 1024 + lane * 16;
    half8 h0 = *(const half8*)xr;
    half8 h1 = *(const half8*)(xr + 8);
    float x[16];
    #pragma unroll
    for (int i = 0; i < 8; i++) { x[i] = (float)h0[i]; x[8 + i] = (float)h1[i]; }
    float sx = 0.f, sx2 = 0.f;
    #pragma unroll
    for (int i = 0; i < 16; i++) { sx += x[i]; sx2 += x[i] * x[i]; }
    #pragma unroll
    for (int o = 32; o > 0; o >>= 1) {
        sx += __shfl_xor(sx, o);
        sx2 += __shfl_xor(sx2, o);
    }
    float mu = sx * (1.f / 1024.f);
    float var = sx2 * (1.f / 1024.f) - mu * mu;
    float rstd = 1.f / sqrtf(var + 1e-5f);

    const float4* gp = (const float4*)(G + lane * 16);
    const float4* bp = (const float4*)(Bt + lane * 16);
    float l[16];
    #pragma unroll
    for (int i = 0; i < 4; i++) {
        float4 gv = gp[i], bv = bp[i];
        l[i * 4 + 0] = (x[i * 4 + 0] - mu) * rstd * gv.x + bv.x;
        l[i * 4 + 1] = (x[i * 4 + 1] - mu) * rstd * gv.y + bv.y;
        l[i * 4 + 2] = (x[i * 4 + 2] - mu) * rstd * gv.z + bv.z;
        l[i * 4 + 3] = (x[i * 4 + 3] - mu) * rstd * gv.w + bv.w;
    }
    float msq = 0.f, am = 0.f;
    #pragma unroll
    for (int i = 0; i < 16; i++) { msq += l[i] * l[i]; am = fmaxf(am, fabsf(l[i])); }
    #pragma unroll
    for (int o = 32; o > 0; o >>= 1) {
        msq += __shfl_xor(msq, o);
        am = fmaxf(am, __shfl_xor(am, o));
    }
    float r2 = 1.f / sqrtf(msq * (1.f / 1024.f) + 1e-6f);
    float mx = fmaxf(am * r2, 1e-5f);
    float s = 127.f / mx;
    int pk[4];
    #pragma unroll
    for (int i = 0; i < 4; i++) {
        int q0 = quant8((l[i * 4 + 0] * r2) * s);
        int q1 = quant8((l[i * 4 + 1] * r2) * s);
        int q2 = quant8((l[i * 4 + 2] * r2) * s);
        int q3 = quant8((l[i * 4 + 3] * r2) * s);
        pk[i] = (q0 & 0xff) | ((q1 & 0xff) << 8) | ((q2 & 0xff) << 16) | ((q3 & 0xff) << 24);
    }
    int4v pv = {pk[0], pk[1], pk[2], pk[3]};
    ((int4v*)(O8 + (size_t)row * 1024))[lane] = pv;
    if (lane == 0) OS[row] = mx * (1.f / 127.f);
}

// ------------------------------------------------------------------ launch ---
extern "C" void kernel_launch(void* const* d_in, const int* in_sizes, int n_in,
                              void* d_out, int out_size, void* d_ws, size_t ws_size,
                              hipStream_t stream)
{
    const float* X  = (const float*)d_in[0];
    const float* Y  = (const float*)d_in[1];
    const float* WQ = (const float*)d_in[2];
    const float* WK = (const float*)d_in[3];
    const float* WV = (const float*)d_in[4];
    const float* WO = (const float*)d_in[5];
    const float* G  = (const float*)d_in[6];
    const float* Bt = (const float*)d_in[7];

    // workspace layout (~64 MB)
    char* ws = (char*)d_ws;
    float*  betas = (float*)ws;                        // 16 B
    double* part  = (double*)(ws + 256);               // 1536 B
    char* w8  = ws + 4096;                             // 3 MB (wq | wk+wv | wo)
    char* x8  = w8 + (3 << 20);                        // 16 MB (reused as o8)
    char* y8  = x8 + (16 << 20);                       // 4 MB
    float* xs = (float*)(y8 + (4 << 20));              // 64 KB
    float* ys = xs + 16384;                            // 16 KB
    float* os = ys + 4096;                             // 64 KB
    _Float16* qf16 = (_Float16*)(os + 16384);          // 32 MB (attn in-place)
    _Float16* kf16 = qf16 + (size_t)16384 * 1024;      // 4 MB
    _Float16* vt16 = kf16 + (size_t)4096 * 512;        // 4 MB
    char* wq8 = w8;
    char* kv8 = w8 + (1 << 20);
    char* wo8 = w8 + (2 << 20);
    char* o8  = x8;

    absmean_all<<<192, 256, 0, stream>>>(WQ, WK, WV, WO, part);
    betas_kernel<<<1, 256, 0, stream>>>(part, betas);
    wquant_all<<<3072, 256, 0, stream>>>(WQ, WK, WV, WO, (signed char*)w8, betas);

    act_quant<<<4096, 256, 0, stream>>>(X, (signed char*)x8, xs);
    act_quant<<<1024, 256, 0, stream>>>(Y, (signed char*)y8, ys);

    // q projection -> f16, 1/sqrt(64) folded in
    gemm_i8<<<dim3(8, 128), 256, 0, stream>>>(
        (signed char*)x8, (signed char*)wq8, nullptr, qf16, nullptr, nullptr,
        1024, 1024, xs, betas, 0, 0, 1024, 0.125f, 1);
    // fused k|v projection -> kf16 + transposed vt16
    gemm_i8<<<dim3(8, 32), 256, 0, stream>>>(
        (signed char*)y8, (signed char*)kv8, nullptr, nullptr, kf16, vt16,
        1024, 1024, ys, betas, 1, 2, 512, 1.f, 2);

    attn_mfma<<<4096, 256, 0, stream>>>(qf16, kf16, vt16, qf16);

    ln_quant<<<4096, 256, 0, stream>>>(qf16, G, Bt, (signed char*)o8, os);

    // out projection -> f32 d_out
    gemm_i8<<<dim3(8, 128), 256, 0, stream>>>(
        (signed char*)o8, (signed char*)wo8, (float*)d_out, nullptr, nullptr, nullptr,
        1024, 1024, os, betas, 3, 3, 1024, 1.f, 0);
}

// Round 5
// 390.278 us; speedup vs baseline: 2.5224x; 1.1527x over previous
//
#include <hip/hip_runtime.h>
#include <hip/hip_bf16.h>

typedef int int4v __attribute__((ext_vector_type(4)));
typedef float float4v __attribute__((ext_vector_type(4)));
typedef _Float16 half8 __attribute__((ext_vector_type(8)));

#define DEV __device__ __forceinline__

DEV signed char quant8(float v) {
    int q = (int)rintf(v);
    q = q < -128 ? -128 : (q > 127 ? 127 : q);
    return (signed char)q;
}

DEV int tern1(float v) {
    int q = (int)rintf(v);
    q = q < -1 ? -1 : (q > 1 ? 1 : q);
    return q;
}

// async global->LDS, 16B per lane; LDS dest = wave-uniform base + lane*16
DEV void gl2lds16(const void* g, void* l) {
    __builtin_amdgcn_global_load_lds(
        (const __attribute__((address_space(1))) void*)g,
        (__attribute__((address_space(3))) void*)l, 16, 0, 0);
}

// ---------------------------------------------------------------- weights ---
__global__ __launch_bounds__(256) void absmean_all(
    const float* __restrict__ WQ, const float* __restrict__ WK,
    const float* __restrict__ WV, const float* __restrict__ WO,
    double* __restrict__ part)
{
    __shared__ double red[256];
    int bx = blockIdx.x, t = threadIdx.x;
    const float* W; int rel;
    if (bx < 64)       { W = WQ; rel = bx; }
    else if (bx < 96)  { W = WK; rel = bx - 64; }
    else if (bx < 128) { W = WV; rel = bx - 96; }
    else               { W = WO; rel = bx - 128; }
    size_t base = (size_t)rel * 16384;
    double acc = 0.0;
    for (int i = t; i < 16384; i += 256) acc += (double)fabsf(W[base + i]);
    red[t] = acc; __syncthreads();
    #pragma unroll
    for (int o = 128; o > 0; o >>= 1) {
        if (t < o) red[t] += red[t + o];
        __syncthreads();
    }
    if (t == 0) part[bx] = red[0];
}

__global__ __launch_bounds__(256) void betas_kernel(
    const double* __restrict__ part, float* __restrict__ betas)
{
    int t = threadIdx.x, w = t >> 6, lane = t & 63;
    const int offs[4]   = {0, 64, 96, 128};
    const int cnts[4]   = {64, 32, 32, 64};
    const int counts[4] = {1048576, 524288, 524288, 1048576};
    double v = (lane < cnts[w]) ? part[offs[w] + lane] : 0.0;
    #pragma unroll
    for (int o = 32; o > 0; o >>= 1) v += __shfl_down(v, o);
    if (lane == 0) betas[w] = fmaxf((float)(v / (double)counts[w]), 1e-5f);
}

__global__ __launch_bounds__(256) void wquant_all(
    const float* __restrict__ WQ, const float* __restrict__ WK,
    const float* __restrict__ WV, const float* __restrict__ WO,
    signed char* __restrict__ w8, const float* __restrict__ betas)
{
    int bx = blockIdx.x;
    const float* W; signed char* O; float inv; int rel;
    if (bx < 1024)      { W = WQ; O = w8;                           rel = bx;        inv = 1.f / betas[0]; }
    else if (bx < 1536) { W = WK; O = w8 + (1 << 20);               rel = bx - 1024; inv = 1.f / betas[1]; }
    else if (bx < 2048) { W = WV; O = w8 + (1 << 20) + (512 << 10); rel = bx - 1536; inv = 1.f / betas[2]; }
    else                { W = WO; O = w8 + (2 << 20);               rel = bx - 2048; inv = 1.f / betas[3]; }
    int i = rel * 256 + threadIdx.x;
    float4 u = ((const float4*)W)[i];
    int q0 = tern1(u.x * inv);
    int q1 = tern1(u.y * inv);
    int q2 = tern1(u.z * inv);
    int q3 = tern1(u.w * inv);
    int packed = (q0 & 0xff) | ((q1 & 0xff) << 8) | ((q2 & 0xff) << 16) | ((q3 & 0xff) << 24);
    ((int*)O)[i] = packed;
}

// ------------------------------------------------------------ activations ---
__global__ __launch_bounds__(256) void act_quant(
    const float* __restrict__ X, signed char* __restrict__ X8,
    float* __restrict__ RS)
{
    int row = blockIdx.x * 4 + (threadIdx.x >> 6);
    int lane = threadIdx.x & 63;
    const float4* xr = (const float4*)(X + (size_t)row * 1024) + lane * 4;
    float4 u[4];
    #pragma unroll
    for (int i = 0; i < 4; i++) u[i] = xr[i];
    float ss = 0.f, am = 0.f;
    #pragma unroll
    for (int i = 0; i < 4; i++) {
        ss += u[i].x * u[i].x + u[i].y * u[i].y + u[i].z * u[i].z + u[i].w * u[i].w;
        am = fmaxf(am, fmaxf(fmaxf(fabsf(u[i].x), fabsf(u[i].y)),
                             fmaxf(fabsf(u[i].z), fabsf(u[i].w))));
    }
    #pragma unroll
    for (int o = 32; o > 0; o >>= 1) {
        ss += __shfl_xor(ss, o);
        am = fmaxf(am, __shfl_xor(am, o));
    }
    float r = 1.f / sqrtf(ss * (1.f / 1024.f) + 1e-6f);
    float m = fmaxf(am * r, 1e-5f);
    float s = 127.f / m;
    int pk[4];
    #pragma unroll
    for (int i = 0; i < 4; i++) {
        int q0 = quant8((u[i].x * r) * s);
        int q1 = quant8((u[i].y * r) * s);
        int q2 = quant8((u[i].z * r) * s);
        int q3 = quant8((u[i].w * r) * s);
        pk[i] = (q0 & 0xff) | ((q1 & 0xff) << 8) | ((q2 & 0xff) << 16) | ((q3 & 0xff) << 24);
    }
    int4v pv = {pk[0], pk[1], pk[2], pk[3]};
    ((int4v*)(X8 + (size_t)row * 1024))[lane] = pv;
    if (lane == 0) RS[row] = m * (1.f / 127.f);
}

// ------------------------------------------------------------------ GEMM ----
// C[M,N] = A[M,K](int8) . B[N,K](int8 ternary)^T, dequant rowscale*beta.
// global_load_lds width-16 staging into unpadded [128][64] tiles (m97 style).
// mode 0: f32 out  mode 1: f16 out (q)  mode 2: k->kf16 / v->vt16 transposed
__global__ __launch_bounds__(256) void gemm_i8(
    const signed char* __restrict__ A, const signed char* __restrict__ B,
    float* __restrict__ outF, _Float16* __restrict__ outH,
    _Float16* __restrict__ outK, _Float16* __restrict__ outV,
    int N, int K,
    const float* __restrict__ rowscale, const float* __restrict__ betas,
    int b0i, int b1i, int split, float extra, int mode)
{
    __shared__ __align__(16) signed char As[128 * 64];
    __shared__ __align__(16) signed char Bs[128 * 64];
    const int tid = threadIdx.x;
    const int lane = tid & 63, wid = tid >> 6;
    const int wr = wid >> 1, wc = wid & 1;
    const int lr = lane & 15, quad = lane >> 4;
    const int bM = blockIdx.y, bN = blockIdx.x;

    int4v zero = {0, 0, 0, 0};
    int4v acc[4][4];
    #pragma unroll
    for (int i = 0; i < 4; i++)
        #pragma unroll
        for (int j = 0; j < 4; j++) acc[i][j] = zero;

    // staging addressing: chunk c = wid*2+i covers tile rows [c*16, c*16+16);
    // lane supplies row c*16 + (lane>>2), bytes (lane&3)*16; LDS dest is
    // uniform base + lane*16 (forced layout == row-major [16][64]).
    const int srow = wid * 32 + (lane >> 2);
    const int soff = (lane & 3) * 16;
    const signed char* gA0 = A + (size_t)(bM * 128 + srow) * K + soff;
    const signed char* gA1 = gA0 + (size_t)16 * K;
    const signed char* gB0 = B + (size_t)(bN * 128 + srow) * K + soff;
    const signed char* gB1 = gB0 + (size_t)16 * K;
    signed char* lA0 = As + wid * 2048;
    signed char* lA1 = lA0 + 1024;
    signed char* lB0 = Bs + wid * 2048;
    signed char* lB1 = lB0 + 1024;

    for (int kb = 0; kb < K; kb += 64) {
        __syncthreads();
        gl2lds16(gA0 + kb, lA0);
        gl2lds16(gA1 + kb, lA1);
        gl2lds16(gB0 + kb, lB0);
        gl2lds16(gB1 + kb, lB1);
        __syncthreads();
        int4v af[4], bfr[4];
        #pragma unroll
        for (int tm = 0; tm < 4; tm++)
            af[tm] = *(const int4v*)(As + (wr * 64 + tm * 16 + lr) * 64 + quad * 16);
        #pragma unroll
        for (int tn = 0; tn < 4; tn++)
            bfr[tn] = *(const int4v*)(Bs + (wc * 64 + tn * 16 + lr) * 64 + quad * 16);
        #pragma unroll
        for (int tm = 0; tm < 4; tm++)
            #pragma unroll
            for (int tn = 0; tn < 4; tn++)
                acc[tm][tn] = __builtin_amdgcn_mfma_i32_16x16x64_i8(af[tm], bfr[tn], acc[tm][tn], 0, 0, 0);
    }

    const float s0 = betas[b0i] * extra, s1 = betas[b1i] * extra;
    #pragma unroll
    for (int tm = 0; tm < 4; tm++) {
        #pragma unroll
        for (int r = 0; r < 4; r++) {
            int grow = bM * 128 + wr * 64 + tm * 16 + quad * 4 + r;
            float rs = rowscale[grow];
            #pragma unroll
            for (int tn = 0; tn < 4; tn++) {
                int col = bN * 128 + wc * 64 + tn * 16 + lr;
                float v = (float)acc[tm][tn][r] * rs * (col < split ? s0 : s1);
                if (mode == 0) {
                    outF[(size_t)grow * N + col] = v;
                } else if (mode == 1) {
                    outH[(size_t)grow * 1024 + col] = (_Float16)v;
                } else {
                    if (col < 512)
                        outK[(size_t)grow * 512 + col] = (_Float16)v;
                    else
                        outV[((size_t)(grow >> 8) * 512 + (col - 512)) * 256 + (grow & 255)] = (_Float16)v;
                }
            }
        }
    }
}

// -------------------------------------------------------------- attention ---
// MFMA GQA. Wave = 16 query rows of one (b,h,g). K (256x72 f16, padded) and
// V^T (64x264 f16) bulk-staged into one overlaid LDS region with coalesced
// half8 copies; fragments via ds_read_b128 (phase-disjoint banks). Full
// S=256 scores in registers, exact softmax, P via per-wave LDS. In-place.
__global__ __launch_bounds__(256) void attn_mfma(
    const _Float16* Qh, const _Float16* __restrict__ Kh,
    const _Float16* __restrict__ Vt, _Float16* Oh)
{
    __shared__ __align__(16) _Float16 KVs[256 * 72];      // 36864 B (V: 64x264=33792)
    __shared__ __align__(16) _Float16 Pm[4 * 16 * 136];   // 17408 B

    const int tid = threadIdx.x;
    const int lane = tid & 63;
    const int w = tid >> 6;
    const int lq = lane & 15;
    const int quad = lane >> 4;

    const int bx = blockIdx.x;       // b(16) x h(8) x g(2) x nt(16)
    const int nt = bx & 15, g = (bx >> 4) & 1, h = (bx >> 5) & 7, b = bx >> 8;
    const int rbase = b * 1024 + nt * 64 + w * 16;
    const int qcol0 = (h * 2 + g) * 64;

    // Q fragments (A-layout), 1/8 scale folded in q-gemm epilogue
    half8 aq[2];
    #pragma unroll
    for (int ks = 0; ks < 2; ks++)
        aq[ks] = *(const half8*)(Qh + (size_t)(rbase + lq) * 1024 + qcol0 + ks * 32 + quad * 8);

    // ---- stage K tile: rows = tokens, stride 72 f16
    {
        int row = tid >> 3, c = tid & 7;
        const _Float16* kg = Kh + (size_t)(b * 256 + row) * 512 + h * 64 + c * 8;
        _Float16* ld = KVs + row * 72 + c * 8;
        #pragma unroll
        for (int j = 0; j < 8; j++)
            *(half8*)(ld + 32 * j * 72) = *(const half8*)(kg + (size_t)32 * j * 512);
    }
    __syncthreads();

    // ---- QK^T
    float4v acc[16];
    float4v zf = {0.f, 0.f, 0.f, 0.f};
    #pragma unroll
    for (int t = 0; t < 16; t++) acc[t] = zf;
    #pragma unroll
    for (int t = 0; t < 16; t++) {
        #pragma unroll
        for (int ks = 0; ks < 2; ks++) {
            half8 bk = *(const half8*)&KVs[(t * 16 + lq) * 72 + ks * 32 + quad * 8];
            acc[t] = __builtin_amdgcn_mfma_f32_16x16x32_f16(aq[ks], bk, acc[t], 0, 0, 0);
        }
    }

    // ---- exact full-row softmax (row = quad*4+r, cols spread over 16 lanes)
    float lsum[4];
    #pragma unroll
    for (int r = 0; r < 4; r++) {
        float m = acc[0][r];
        #pragma unroll
        for (int t = 1; t < 16; t++) m = fmaxf(m, acc[t][r]);
        m = fmaxf(m, __shfl_xor(m, 1));
        m = fmaxf(m, __shfl_xor(m, 2));
        m = fmaxf(m, __shfl_xor(m, 4));
        m = fmaxf(m, __shfl_xor(m, 8));
        float l = 0.f;
        #pragma unroll
        for (int t = 0; t < 16; t++) {
            float p = __expf(acc[t][r] - m);
            acc[t][r] = p;
            l += p;
        }
        l += __shfl_xor(l, 1);
        l += __shfl_xor(l, 2);
        l += __shfl_xor(l, 4);
        l += __shfl_xor(l, 8);
        lsum[r] = l;
    }

    __syncthreads();   // all waves done reading K region

    // ---- stage V^T tile: rows = head dims (64), stride 264 f16
    {
        int row = tid >> 5, c = tid & 31;
        const _Float16* vg = Vt + ((size_t)b * 512 + h * 64 + row) * 256 + c * 8;
        _Float16* ld = KVs + row * 264 + c * 8;
        #pragma unroll
        for (int j = 0; j < 8; j++)
            *(half8*)(ld + 8 * j * 264) = *(const half8*)(vg + (size_t)8 * j * 256);
    }
    __syncthreads();

    // ---- PV in two S-halves; P round-trips through per-wave LDS
    _Float16* Pw = Pm + w * (16 * 136);
    float4v oacc[4];
    #pragma unroll
    for (int dt = 0; dt < 4; dt++) oacc[dt] = zf;

    #pragma unroll
    for (int half_ = 0; half_ < 2; half_++) {
        #pragma unroll
        for (int t = 0; t < 8; t++) {
            int tg = half_ * 8 + t;
            #pragma unroll
            for (int r = 0; r < 4; r++)
                Pw[(quad * 4 + r) * 136 + t * 16 + lq] = (_Float16)acc[tg][r];
        }
        #pragma unroll
        for (int k2 = 0; k2 < 4; k2++) {
            half8 ap = *(const half8*)&Pw[lq * 136 + k2 * 32 + quad * 8];
            #pragma unroll
            for (int dt = 0; dt < 4; dt++) {
                half8 bv = *(const half8*)&KVs[(dt * 16 + lq) * 264 +
                                               half_ * 128 + k2 * 32 + quad * 8];
                oacc[dt] = __builtin_amdgcn_mfma_f32_16x16x32_f16(ap, bv, oacc[dt], 0, 0, 0);
            }
        }
    }

    // ---- epilogue: normalize, write f16 in-place
    float inv[4];
    #pragma unroll
    for (int r = 0; r < 4; r++) inv[r] = 1.f / lsum[r];
    #pragma unroll
    for (int dt = 0; dt < 4; dt++) {
        #pragma unroll
        for (int r = 0; r < 4; r++) {
            Oh[(size_t)(rbase + quad * 4 + r) * 1024 + qcol0 + dt * 16 + lq] =
                (_Float16)(oacc[dt][r] * inv[r]);
        }
    }
}

// ---------------------------------------------------- LayerNorm + re-quant ---
__global__ __launch_bounds__(256) void ln_quant(
    const _Float16* __restrict__ AO, const float* __restrict__ G,
    const float* __restrict__ Bt, signed char* __restrict__ O8,
    float* __restrict__ OS)
{
    int row = blockIdx.x * 4 + (threadIdx.x >> 6);
    int lane = threadIdx.x & 63;
    const _Float16* xr = AO + (size_t)row * 1024 + lane * 16;
    half8 h0 = *(const half8*)xr;
    half8 h1 = *(const half8*)(xr + 8);
    float x[16];
    #pragma unroll
    for (int i = 0; i < 8; i++) { x[i] = (float)h0[i]; x[8 + i] = (float)h1[i]; }
    float sx = 0.f, sx2 = 0.f;
    #pragma unroll
    for (int i = 0; i < 16; i++) { sx += x[i]; sx2 += x[i] * x[i]; }
    #pragma unroll
    for (int o = 32; o > 0; o >>= 1) {
        sx += __shfl_xor(sx, o);
        sx2 += __shfl_xor(sx2, o);
    }
    float mu = sx * (1.f / 1024.f);
    float var = sx2 * (1.f / 1024.f) - mu * mu;
    float rstd = 1.f / sqrtf(var + 1e-5f);

    const float4* gp = (const float4*)(G + lane * 16);
    const float4* bp = (const float4*)(Bt + lane * 16);
    float l[16];
    #pragma unroll
    for (int i = 0; i < 4; i++) {
        float4 gv = gp[i], bv = bp[i];
        l[i * 4 + 0] = (x[i * 4 + 0] - mu) * rstd * gv.x + bv.x;
        l[i * 4 + 1] = (x[i * 4 + 1] - mu) * rstd * gv.y + bv.y;
        l[i * 4 + 2] = (x[i * 4 + 2] - mu) * rstd * gv.z + bv.z;
        l[i * 4 + 3] = (x[i * 4 + 3] - mu) * rstd * gv.w + bv.w;
    }
    float msq = 0.f, am = 0.f;
    #pragma unroll
    for (int i = 0; i < 16; i++) { msq += l[i] * l[i]; am = fmaxf(am, fabsf(l[i])); }
    #pragma unroll
    for (int o = 32; o > 0; o >>= 1) {
        msq += __shfl_xor(msq, o);
        am = fmaxf(am, __shfl_xor(am, o));
    }
    float r2 = 1.f / sqrtf(msq * (1.f / 1024.f) + 1e-6f);
    float mx = fmaxf(am * r2, 1e-5f);
    float s = 127.f / mx;
    int pk[4];
    #pragma unroll
    for (int i = 0; i < 4; i++) {
        int q0 = quant8((l[i * 4 + 0] * r2) * s);
        int q1 = quant8((l[i * 4 + 1] * r2) * s);
        int q2 = quant8((l[i * 4 + 2] * r2) * s);
        int q3 = quant8((l[i * 4 + 3] * r2) * s);
        pk[i] = (q0 & 0xff) | ((q1 & 0xff) << 8) | ((q2 & 0xff) << 16) | ((q3 & 0xff) << 24);
    }
    int4v pv = {pk[0], pk[1], pk[2], pk[3]};
    ((int4v*)(O8 + (size_t)row * 1024))[lane] = pv;
    if (lane == 0) OS[row] = mx * (1.f / 127.f);
}

// ------------------------------------------------------------------ launch ---
extern "C" void kernel_launch(void* const* d_in, const int* in_sizes, int n_in,
                              void* d_out, int out_size, void* d_ws, size_t ws_size,
                              hipStream_t stream)
{
    const float* X  = (const float*)d_in[0];
    const float* Y  = (const float*)d_in[1];
    const float* WQ = (const float*)d_in[2];
    const float* WK = (const float*)d_in[3];
    const float* WV = (const float*)d_in[4];
    const float* WO = (const float*)d_in[5];
    const float* G  = (const float*)d_in[6];
    const float* Bt = (const float*)d_in[7];

    // workspace layout (~64 MB)
    char* ws = (char*)d_ws;
    float*  betas = (float*)ws;                        // 16 B
    double* part  = (double*)(ws + 256);               // 1536 B
    char* w8  = ws + 4096;                             // 3 MB (wq | wk+wv | wo)
    char* x8  = w8 + (3 << 20);                        // 16 MB (reused as o8)
    char* y8  = x8 + (16 << 20);                       // 4 MB
    float* xs = (float*)(y8 + (4 << 20));              // 64 KB
    float* ys = xs + 16384;                            // 16 KB
    float* os = ys + 4096;                             // 64 KB
    _Float16* qf16 = (_Float16*)(os + 16384);          // 32 MB (attn in-place)
    _Float16* kf16 = qf16 + (size_t)16384 * 1024;      // 4 MB
    _Float16* vt16 = kf16 + (size_t)4096 * 512;        // 4 MB
    char* wq8 = w8;
    char* kv8 = w8 + (1 << 20);
    char* wo8 = w8 + (2 << 20);
    char* o8  = x8;

    absmean_all<<<192, 256, 0, stream>>>(WQ, WK, WV, WO, part);
    betas_kernel<<<1, 256, 0, stream>>>(part, betas);
    wquant_all<<<3072, 256, 0, stream>>>(WQ, WK, WV, WO, (signed char*)w8, betas);

    act_quant<<<4096, 256, 0, stream>>>(X, (signed char*)x8, xs);
    act_quant<<<1024, 256, 0, stream>>>(Y, (signed char*)y8, ys);

    // q projection -> f16, 1/sqrt(64) folded in
    gemm_i8<<<dim3(8, 128), 256, 0, stream>>>(
        (signed char*)x8, (signed char*)wq8, nullptr, qf16, nullptr, nullptr,
        1024, 1024, xs, betas, 0, 0, 1024, 0.125f, 1);
    // fused k|v projection -> kf16 + transposed vt16
    gemm_i8<<<dim3(8, 32), 256, 0, stream>>>(
        (signed char*)y8, (signed char*)kv8, nullptr, nullptr, kf16, vt16,
        1024, 1024, ys, betas, 1, 2, 512, 1.f, 2);

    attn_mfma<<<4096, 256, 0, stream>>>(qf16, kf16, vt16, qf16);

    ln_quant<<<4096, 256, 0, stream>>>(qf16, G, Bt, (signed char*)o8, os);

    // out projection -> f32 d_out
    gemm_i8<<<dim3(8, 128), 256, 0, stream>>>(
        (signed char*)o8, (signed char*)wo8, (float*)d_out, nullptr, nullptr, nullptr,
        1024, 1024, os, betas, 3, 3, 1024, 1.f, 0);
}